// Round 6
// baseline (3145.233 us; speedup 1.0000x reference)
//
#include <hip/hip_runtime.h>

typedef __attribute__((ext_vector_type(8))) _Float16 f16x8;
typedef __attribute__((ext_vector_type(4))) float f32x4;
typedef unsigned short u16;

#define BB 64
#define NPIX 1024
#define NELEM (BB*64*NPIX)           // 4194304
#define NRT 8                        // row-tiles of 4 rows

// LDS input layout: [pixel 6*34][chunk-slot swizzled 8x8 u16] (single f16 plane)
#define PLANE (6*34*64)              // 13056 u16

__device__ __forceinline__ int swz8(int c8, int p) {
    return (c8 + ((p + (p >> 2)) & 7)) & 7;
}
__device__ __forceinline__ u16 f2h(float x) {
    _Float16 h = (_Float16)x;
    return __builtin_bit_cast(u16, h);
}
__device__ __forceinline__ float h2f(u16 u) {
    return (float)__builtin_bit_cast(_Float16, u);
}

// ---------------------------------------------------------------------------
__global__ __launch_bounds__(256) void prep_w_k(
    const float* __restrict__ w, u16* __restrict__ wt)
{
    int t = blockIdx.x*256 + threadIdx.x;
    if (t >= 4608) return;
    int lane = t & 63;
    int f = t >> 6;              // 0..71
    int g = f & 7;               // kc*4 + coutblk
    int tap = f >> 3;            // 0..8
    int coutblk = g & 3;
    int kc = g >> 2;
    int cout = coutblk*16 + (lane & 15);
    int quad = lane >> 4;
    u16 v[8];
#pragma unroll
    for (int j = 0; j < 8; ++j) {
        int cin = kc*32 + quad*8 + j;
        v[j] = f2h(w[((size_t)cout*65 + (cin+1))*9 + tap]);
    }
    u16* dst = wt + ((size_t)tap*4096 + (g*64 + lane)*8);
    *(ushort4*)(dst)     = make_ushort4(v[0], v[1], v[2], v[3]);
    *(ushort4*)(dst + 4) = make_ushort4(v[4], v[5], v[6], v[7]);
}

__global__ __launch_bounds__(256) void smap_k(
    const float* __restrict__ w, float* __restrict__ smap)
{
    int t = blockIdx.x*256 + threadIdx.x;
    int cout = t >> 10;
    int pix = t & 1023;
    int y = pix >> 5, x = pix & 31;
    float s = 0.f;
#pragma unroll
    for (int dy = 0; dy < 3; ++dy)
#pragma unroll
        for (int dx = 0; dx < 3; ++dx) {
            int yy = y + dy - 1, xx = x + dx - 1;
            if ((unsigned)yy < 32u && (unsigned)xx < 32u)
                s += w[(size_t)cout*65*9 + dy*3 + dx];
        }
    smap[t] = s;
}

// ===========================================================================
// VARIANT A: 256-thread blocks (4 waves, 4 blocks/CU), k stored as fp32.
//  MODE 0: v = src0 (fp32, raw)
//  MODE 1: v = src0 + kbf[ch] + sum_{jj<NK} kaf[jj][ch]*k_jj   (k fp32)
//          (WRITEY: also store v as fp32 to yout, interior rows only)
//  MODE 2: v = relu(kaf[0][ch]*h2f(srcb) + kbf[ch]); output k fp32
// ===========================================================================
template<int MODE, int NK, bool WRITEY>
__global__ __launch_bounds__(256, 4) void conv32_k(
    const float* __restrict__ src0, const u16* __restrict__ srcb,
    const float* __restrict__ kp0, const float* __restrict__ kp1,
    const float* __restrict__ kp2, const float* __restrict__ kp3,
    const float* __restrict__ kp4, const float* __restrict__ kp5,
    float* __restrict__ yout,
    float* __restrict__ part,
    const float* __restrict__ gns, const float* __restrict__ gnb,
    const float* __restrict__ gks, const float* __restrict__ gkb,
    const u16* __restrict__ wt, const float* __restrict__ smap,
    const float* __restrict__ bias, u16* __restrict__ outh,
    float* __restrict__ outk, float tval,
    int slot_in, int slot_out,
    float a1, float a2, float a3, float a4, float a5, float a6)
{
    __shared__ u16 lds_in[PLANE];            // 26112 B
    __shared__ float kaf[6][64];
    __shared__ float kbf[64];
    __shared__ float ps[256], pss[256];      // [row4][cout64]
    __shared__ float rg[64], rgq[64];

    const int rt  = blockIdx.x;              // 0..7
    const int b   = blockIdx.y;
    const int tid = threadIdx.x;
    const int wv   = tid >> 6;               // 0..3
    const int lane = tid & 63;
    const int quad = lane >> 4;
    const int n15  = lane & 15;
    const int r0   = wv;                     // row in tile

    float4 Y0[3], Y1[3];
    ushort4 H0[3], H1[3];

    auto prim_load = [&](int hh) {
#pragma unroll
        for (int uu = 0; uu < 3; ++uu) {
            int u = hh*768 + tid + uu*256;
            int q4 = u & 7;
            int t2 = u >> 3;
            int rr = t2 % 6;
            int c2 = t2 / 6;
            int gr = rt*4 + rr - 1;
            if ((unsigned)gr < 32u) {
                const size_t base = (((size_t)b*64 + c2*2)*32 + gr)*32 + q4*4;
                if constexpr (MODE == 2) {
                    H0[uu] = *(const ushort4*)(srcb + base);
                    H1[uu] = *(const ushort4*)(srcb + base + 1024);
                } else {
                    Y0[uu] = *(const float4*)(src0 + base);
                    Y1[uu] = *(const float4*)(src0 + base + 1024);
                }
            }
        }
    };

    auto stage_finish = [&](int hh) {
#pragma unroll
        for (int uu = 0; uu < 3; ++uu) {
            int u = hh*768 + tid + uu*256;
            int q4 = u & 7;
            int t2 = u >> 3;
            int rr = t2 % 6;
            int c2 = t2 / 6;
            int gr = rt*4 + rr - 1;
            bool ok = (unsigned)gr < 32u;
            int ch0 = c2*2, ch1 = ch0 + 1;
            float4 a0 = make_float4(0.f,0.f,0.f,0.f), a1v = a0;
            if (ok) {
                const size_t base = (((size_t)b*64 + ch0)*32 + gr)*32 + q4*4;
                if constexpr (MODE == 2) {
                    float A0 = kaf[0][ch0], B0 = kbf[ch0];
                    float A1 = kaf[0][ch1], B1 = kbf[ch1];
                    a0.x = fmaxf(fmaf(h2f(H0[uu].x),A0,B0), 0.f);
                    a0.y = fmaxf(fmaf(h2f(H0[uu].y),A0,B0), 0.f);
                    a0.z = fmaxf(fmaf(h2f(H0[uu].z),A0,B0), 0.f);
                    a0.w = fmaxf(fmaf(h2f(H0[uu].w),A0,B0), 0.f);
                    a1v.x = fmaxf(fmaf(h2f(H1[uu].x),A1,B1), 0.f);
                    a1v.y = fmaxf(fmaf(h2f(H1[uu].y),A1,B1), 0.f);
                    a1v.z = fmaxf(fmaf(h2f(H1[uu].z),A1,B1), 0.f);
                    a1v.w = fmaxf(fmaf(h2f(H1[uu].w),A1,B1), 0.f);
                } else {
                    a0 = Y0[uu]; a1v = Y1[uu];
                    if constexpr (MODE == 1) {
                        float f0 = kbf[ch0], f1 = kbf[ch1];
                        a0.x += f0; a0.y += f0; a0.z += f0; a0.w += f0;
                        a1v.x += f1; a1v.y += f1; a1v.z += f1; a1v.w += f1;
                        const float* kps[6] = {kp0, kp1, kp2, kp3, kp4, kp5};
#pragma unroll
                        for (int jj = 0; jj < NK; ++jj) {
                            float4 kv0 = *(const float4*)(kps[jj] + base);
                            float4 kv1 = *(const float4*)(kps[jj] + base + 1024);
                            float fa0 = kaf[jj][ch0], fa1 = kaf[jj][ch1];
                            a0.x = fmaf(fa0, kv0.x, a0.x);
                            a0.y = fmaf(fa0, kv0.y, a0.y);
                            a0.z = fmaf(fa0, kv0.z, a0.z);
                            a0.w = fmaf(fa0, kv0.w, a0.w);
                            a1v.x = fmaf(fa1, kv1.x, a1v.x);
                            a1v.y = fmaf(fa1, kv1.y, a1v.y);
                            a1v.z = fmaf(fa1, kv1.z, a1v.z);
                            a1v.w = fmaf(fa1, kv1.w, a1v.w);
                        }
                    }
                }
                if constexpr (WRITEY) {
                    if (rr >= 1 && rr <= 4) {
                        *(float4*)(yout + base)        = a0;
                        *(float4*)(yout + base + 1024) = a1v;
                    }
                }
            }
            float v0[4] = {a0.x, a0.y, a0.z, a0.w};
            float v1[4] = {a1v.x, a1v.y, a1v.z, a1v.w};
            int c8 = c2 >> 2, cl = c2 & 3;
            int pbase = rr*34 + 1 + q4*4;
#pragma unroll
            for (int j = 0; j < 4; ++j) {
                int p = pbase + j;
                int au = p*64 + swz8(c8, p)*8 + cl*2;
                *(unsigned*)&lds_in[au] =
                    (unsigned)f2h(v0[j]) | ((unsigned)f2h(v1[j]) << 16);
            }
        }
    };

    f32x4 acc[2][2][2] = {};     // [mh][mt][nt]
    auto mfma_kc = [&](int kc) {
#pragma unroll 3
        for (int tap = 0; tap < 9; ++tap) {
            const int dy = tap / 3;
            const int dx = tap - dy*3;
            const int rowoff = (r0 + dy)*34 + dx;
            const u16* wtap = wt + (size_t)tap*4096;
            f16x8 Bf[2];
#pragma unroll
            for (int nt = 0; nt < 2; ++nt) {
                int p = rowoff + nt*16 + n15;
                Bf[nt] = *(const f16x8*)&lds_in[p*64 + swz8(kc*4 + quad, p)*8];
            }
#pragma unroll
            for (int mh = 0; mh < 2; ++mh) {
                f16x8 A0 = *(const f16x8*)&wtap[((kc*4 + mh*2 + 0)*64 + lane)*8];
                f16x8 A1 = *(const f16x8*)&wtap[((kc*4 + mh*2 + 1)*64 + lane)*8];
#pragma unroll
                for (int nt = 0; nt < 2; ++nt) {
                    acc[mh][0][nt] = __builtin_amdgcn_mfma_f32_16x16x32_f16(
                        A0, Bf[nt], acc[mh][0][nt], 0, 0, 0);
                    acc[mh][1][nt] = __builtin_amdgcn_mfma_f32_16x16x32_f16(
                        A1, Bf[nt], acc[mh][1][nt], 0, 0, 0);
                }
            }
        }
    };

    // ==== phase 0 ====
    prim_load(0);

    if constexpr (MODE == 1) {
        if (tid < 64) {
            const float aa[6] = {a1, a2, a3, a4, a5, a6};
            int g = tid >> 1;
            float acb = 0.f;
#pragma unroll
            for (int jj = 0; jj < NK; ++jj) {
                const float4* pp = (const float4*)
                    (part + ((((size_t)(1+jj)*64 + b)*32 + g)*NRT)*2);
                float4 x0 = pp[0], x1 = pp[1], x2 = pp[2], x3 = pp[3];
                float S  = x0.x+x0.z + x1.x+x1.z + x2.x+x2.z + x3.x+x3.z;
                float SS = x0.y+x0.w + x1.y+x1.w + x2.y+x2.w + x3.y+x3.w;
                float mu   = S * (1.f/2048.f);
                float var  = SS * (1.f/2048.f) - mu*mu;
                float rstd = rsqrtf(var + 1e-5f);
                float a = gks[tid]*rstd;
                float c = gkb[tid] - mu*a;
                kaf[jj][tid] = aa[jj]*a;
                acb += aa[jj]*c;
            }
            kbf[tid] = acb;
        }
    } else if constexpr (MODE == 2) {
        if (tid < 64) {
            int g = tid >> 1;
            const float4* pp = (const float4*)
                (part + ((((size_t)slot_in*64 + b)*32 + g)*NRT)*2);
            float4 x0 = pp[0], x1 = pp[1], x2 = pp[2], x3 = pp[3];
            float S  = x0.x+x0.z + x1.x+x1.z + x2.x+x2.z + x3.x+x3.z;
            float SS = x0.y+x0.w + x1.y+x1.w + x2.y+x2.w + x3.y+x3.w;
            float mu   = S * (1.f/2048.f);
            float var  = SS * (1.f/2048.f) - mu*mu;
            float rstd = rsqrtf(var + 1e-5f);
            float a = gns[tid]*rstd;
            kaf[0][tid] = a;
            kbf[tid] = gnb[tid] - mu*a;
        }
    }
    __syncthreads();

    // ==== phase 1 ====
    stage_finish(0);
#pragma unroll
    for (int i = 0; i < 2; ++i) {
        int u = tid + i*256;
        if (u < 384) {
            int c2 = u & 31;
            int t3 = u >> 5;
            int rr = t3 % 6;
            int e  = t3 / 6;
            int p  = rr*34 + e*33;
            int au = p*64 + swz8(c2 >> 2, p)*8 + (c2 & 3)*2;
            *(unsigned*)&lds_in[au] = 0u;
        }
    }
    __syncthreads();

    // ==== phase 2 ====
    prim_load(1);
    mfma_kc(0);
    stage_finish(1);
    __syncthreads();

    // ==== phase 3 ====
    mfma_kc(1);

    // ---- epilogue ----
    const int orow = rt*4 + r0;
#pragma unroll
    for (int mh = 0; mh < 2; ++mh) {
#pragma unroll
        for (int mt = 0; mt < 2; ++mt) {
#pragma unroll
            for (int r = 0; r < 4; ++r) {
                int cout = mh*32 + mt*16 + quad*4 + r;
                float bs = bias[cout];
                const float* sp = smap + (size_t)cout*1024 + orow*32;
                float v0 = acc[mh][mt][0][r] + bs + tval*sp[n15];
                float v1 = acc[mh][mt][1][r] + bs + tval*sp[16 + n15];
                if constexpr (MODE == 2) {
                    float* op = outk + (((size_t)b*64 + cout)*32 + orow)*32;
                    op[n15]      = v0;
                    op[16 + n15] = v1;
                } else {
                    u16* op = outh + (((size_t)b*64 + cout)*32 + orow)*32;
                    op[n15]      = f2h(v0);
                    op[16 + n15] = f2h(v1);
                }
                float s = v0 + v1;
                float q = v0*v0 + v1*v1;
                s += __shfl_xor(s, 1); q += __shfl_xor(q, 1);
                s += __shfl_xor(s, 2); q += __shfl_xor(q, 2);
                s += __shfl_xor(s, 4); q += __shfl_xor(q, 4);
                s += __shfl_xor(s, 8); q += __shfl_xor(q, 8);
                if (n15 == 0) { ps[r0*64 + cout] = s; pss[r0*64 + cout] = q; }
            }
        }
    }
    __syncthreads();
    if (tid < 64) {
        rg[tid]  = ps[tid]  + ps[64+tid]  + ps[128+tid]  + ps[192+tid];
        rgq[tid] = pss[tid] + pss[64+tid] + pss[128+tid] + pss[192+tid];
    }
    __syncthreads();
    if (tid < 32) {
        float S  = rg[2*tid]  + rg[2*tid+1];
        float SS = rgq[2*tid] + rgq[2*tid+1];
        float* pp = part + ((((size_t)slot_out*64 + b)*32 + tid)*NRT + rt)*2;
        pp[0] = S; pp[1] = SS;
    }
}

__global__ __launch_bounds__(256) void final_combine32_k(
    const float* __restrict__ ysrc, float* __restrict__ ydst,
    const float* __restrict__ k0, const float* __restrict__ k1,
    const float* __restrict__ k2, const float* __restrict__ k3,
    const float* __restrict__ k4, const float* __restrict__ k5,
    const float* __restrict__ part,
    const float* __restrict__ g2s, const float* __restrict__ g2b,
    float b0, float b1, float b2, float b3, float b4, float b5)
{
    const int bidx = blockIdx.x;
    const int b = bidx >> 6, ch = bidx & 63, g = ch >> 1;
    const int t = threadIdx.x;
    __shared__ float rs[6][2];
    if (t < 12) {
        int jj = t >> 1, st = t & 1;
        const float* pp = part + ((((size_t)(1+jj)*64 + b)*32 + g)*NRT)*2 + st;
        float v = 0.f;
#pragma unroll
        for (int q = 0; q < NRT; ++q) v += pp[2*q];
        rs[jj][st] = v;
    }
    __syncthreads();
    const float bb[6] = {b0, b1, b2, b3, b4, b5};
    float fa[6], fcs = 0.f;
#pragma unroll
    for (int jj = 0; jj < 6; ++jj) {
        float mu   = rs[jj][0] * (1.f/2048.f);
        float var  = rs[jj][1] * (1.f/2048.f) - mu*mu;
        float rstd = rsqrtf(var + 1e-5f);
        float a = g2s[ch]*rstd;
        float c = g2b[ch] - mu*a;
        fa[jj] = bb[jj]*a;
        fcs   += bb[jj]*c;
    }
    const size_t base = ((size_t)bidx*256 + t)*4;
    float4 r = *(const float4*)(ysrc + base);
    r.x += fcs; r.y += fcs; r.z += fcs; r.w += fcs;
    const float* kp[6] = {k0, k1, k2, k3, k4, k5};
#pragma unroll
    for (int jj = 0; jj < 6; ++jj) {
        float4 kv = *(const float4*)(kp[jj] + base);
        r.x = fmaf(fa[jj], kv.x, r.x);
        r.y = fmaf(fa[jj], kv.y, r.y);
        r.z = fmaf(fa[jj], kv.z, r.z);
        r.w = fmaf(fa[jj], kv.w, r.w);
    }
    *(float4*)(ydst + base) = r;
}

// ===========================================================================
// VARIANT B (fallback, round-2 verbatim): 512-thread blocks, k stored f16.
// ===========================================================================
template<int MODE, int NK, bool WRITEY>
__global__ __launch_bounds__(512, 4) void conv16_k(
    const float* __restrict__ src0, const u16* __restrict__ srcb,
    const u16* __restrict__ kp0, const u16* __restrict__ kp1,
    const u16* __restrict__ kp2, const u16* __restrict__ kp3,
    const u16* __restrict__ kp4, const u16* __restrict__ kp5,
    float* __restrict__ yout,
    float* __restrict__ part,
    const float* __restrict__ gns, const float* __restrict__ gnb,
    const float* __restrict__ gks, const float* __restrict__ gkb,
    const u16* __restrict__ wt, const float* __restrict__ smap,
    const float* __restrict__ bias, u16* __restrict__ out, float tval,
    int slot_in, int slot_out,
    float a1, float a2, float a3, float a4, float a5, float a6)
{
    __shared__ u16 lds_in[PLANE];
    __shared__ float kaf[6][64];
    __shared__ float kbf[64];
    __shared__ float ps[256], pss[256];
    __shared__ float rg[64], rgq[64];

    const int rt  = blockIdx.x;
    const int b   = blockIdx.y;
    const int tid = threadIdx.x;
    const int wv   = tid >> 6;
    const int lane = tid & 63;
    const int quad = lane >> 4;
    const int n15  = lane & 15;
    const int r0   = wv & 3;
    const int mh   = wv >> 2;

    float4 Y0[2], Y1[2];
    ushort4 H0[2], H1[2];

    auto prim_load = [&](int hh) {
#pragma unroll
        for (int uu = 0; uu < 2; ++uu) {
            int ur = tid + uu*512;
            if (ur >= 768) continue;
            int u = hh*768 + ur;
            int q4 = u & 7;
            int t2 = u >> 3;
            int rr = t2 % 6;
            int c2 = t2 / 6;
            int gr = rt*4 + rr - 1;
            if ((unsigned)gr < 32u) {
                const size_t base = (((size_t)b*64 + c2*2)*32 + gr)*32 + q4*4;
                if constexpr (MODE == 2) {
                    H0[uu] = *(const ushort4*)(srcb + base);
                    H1[uu] = *(const ushort4*)(srcb + base + 1024);
                } else {
                    Y0[uu] = *(const float4*)(src0 + base);
                    Y1[uu] = *(const float4*)(src0 + base + 1024);
                }
            }
        }
    };

    auto stage_finish = [&](int hh) {
#pragma unroll
        for (int uu = 0; uu < 2; ++uu) {
            int ur = tid + uu*512;
            if (ur >= 768) continue;
            int u = hh*768 + ur;
            int q4 = u & 7;
            int t2 = u >> 3;
            int rr = t2 % 6;
            int c2 = t2 / 6;
            int gr = rt*4 + rr - 1;
            bool ok = (unsigned)gr < 32u;
            int ch0 = c2*2, ch1 = ch0 + 1;
            float4 a0 = make_float4(0.f,0.f,0.f,0.f), a1v = a0;
            if (ok) {
                const size_t base = (((size_t)b*64 + ch0)*32 + gr)*32 + q4*4;
                if constexpr (MODE == 2) {
                    float A0 = kaf[0][ch0], B0 = kbf[ch0];
                    float A1 = kaf[0][ch1], B1 = kbf[ch1];
                    a0.x = fmaxf(fmaf(h2f(H0[uu].x),A0,B0), 0.f);
                    a0.y = fmaxf(fmaf(h2f(H0[uu].y),A0,B0), 0.f);
                    a0.z = fmaxf(fmaf(h2f(H0[uu].z),A0,B0), 0.f);
                    a0.w = fmaxf(fmaf(h2f(H0[uu].w),A0,B0), 0.f);
                    a1v.x = fmaxf(fmaf(h2f(H1[uu].x),A1,B1), 0.f);
                    a1v.y = fmaxf(fmaf(h2f(H1[uu].y),A1,B1), 0.f);
                    a1v.z = fmaxf(fmaf(h2f(H1[uu].z),A1,B1), 0.f);
                    a1v.w = fmaxf(fmaf(h2f(H1[uu].w),A1,B1), 0.f);
                } else {
                    a0 = Y0[uu]; a1v = Y1[uu];
                    if constexpr (MODE == 1) {
                        float f0 = kbf[ch0], f1 = kbf[ch1];
                        a0.x += f0; a0.y += f0; a0.z += f0; a0.w += f0;
                        a1v.x += f1; a1v.y += f1; a1v.z += f1; a1v.w += f1;
                        const u16* kps[6] = {kp0, kp1, kp2, kp3, kp4, kp5};
#pragma unroll
                        for (int jj = 0; jj < NK; ++jj) {
                            ushort4 kv0 = *(const ushort4*)(kps[jj] + base);
                            ushort4 kv1 = *(const ushort4*)(kps[jj] + base + 1024);
                            float fa0 = kaf[jj][ch0], fa1 = kaf[jj][ch1];
                            a0.x = fmaf(fa0, h2f(kv0.x), a0.x);
                            a0.y = fmaf(fa0, h2f(kv0.y), a0.y);
                            a0.z = fmaf(fa0, h2f(kv0.z), a0.z);
                            a0.w = fmaf(fa0, h2f(kv0.w), a0.w);
                            a1v.x = fmaf(fa1, h2f(kv1.x), a1v.x);
                            a1v.y = fmaf(fa1, h2f(kv1.y), a1v.y);
                            a1v.z = fmaf(fa1, h2f(kv1.z), a1v.z);
                            a1v.w = fmaf(fa1, h2f(kv1.w), a1v.w);
                        }
                    }
                }
                if constexpr (WRITEY) {
                    if (rr >= 1 && rr <= 4) {
                        *(float4*)(yout + base)        = a0;
                        *(float4*)(yout + base + 1024) = a1v;
                    }
                }
            }
            float v0[4] = {a0.x, a0.y, a0.z, a0.w};
            float v1[4] = {a1v.x, a1v.y, a1v.z, a1v.w};
            int c8 = c2 >> 2, cl = c2 & 3;
            int pbase = rr*34 + 1 + q4*4;
#pragma unroll
            for (int j = 0; j < 4; ++j) {
                int p = pbase + j;
                int au = p*64 + swz8(c8, p)*8 + cl*2;
                *(unsigned*)&lds_in[au] =
                    (unsigned)f2h(v0[j]) | ((unsigned)f2h(v1[j]) << 16);
            }
        }
    };

    f32x4 acc[2][2] = {};
    auto mfma_kc = [&](int kc) {
#pragma unroll 3
        for (int tap = 0; tap < 9; ++tap) {
            const int dy = tap / 3;
            const int dx = tap - dy*3;
            const int rowoff = (r0 + dy)*34 + dx;
            const u16* wtap = wt + (size_t)tap*4096;
            f16x8 A[2], Bf[2];
#pragma unroll
            for (int mt = 0; mt < 2; ++mt)
                A[mt] = *(const f16x8*)
                    &wtap[((kc*4 + mh*2 + mt)*64 + lane)*8];
#pragma unroll
            for (int nt = 0; nt < 2; ++nt) {
                int p = rowoff + nt*16 + n15;
                Bf[nt] = *(const f16x8*)&lds_in[p*64 + swz8(kc*4 + quad, p)*8];
            }
#pragma unroll
            for (int mt = 0; mt < 2; ++mt)
#pragma unroll
                for (int nt = 0; nt < 2; ++nt)
                    acc[mt][nt] = __builtin_amdgcn_mfma_f32_16x16x32_f16(
                        A[mt], Bf[nt], acc[mt][nt], 0, 0, 0);
        }
    };

    prim_load(0);

    if constexpr (MODE == 1) {
        if (tid < 64) {
            const float aa[6] = {a1, a2, a3, a4, a5, a6};
            int g = tid >> 1;
            float acb = 0.f;
#pragma unroll
            for (int jj = 0; jj < NK; ++jj) {
                const float4* pp = (const float4*)
                    (part + ((((size_t)(1+jj)*64 + b)*32 + g)*NRT)*2);
                float4 x0 = pp[0], x1 = pp[1], x2 = pp[2], x3 = pp[3];
                float S  = x0.x+x0.z + x1.x+x1.z + x2.x+x2.z + x3.x+x3.z;
                float SS = x0.y+x0.w + x1.y+x1.w + x2.y+x2.w + x3.y+x3.w;
                float mu   = S * (1.f/2048.f);
                float var  = SS * (1.f/2048.f) - mu*mu;
                float rstd = rsqrtf(var + 1e-5f);
                float a = gks[tid]*rstd;
                float c = gkb[tid] - mu*a;
                kaf[jj][tid] = aa[jj]*a;
                acb += aa[jj]*c;
            }
            kbf[tid] = acb;
        }
    } else if constexpr (MODE == 2) {
        if (tid < 64) {
            int g = tid >> 1;
            const float4* pp = (const float4*)
                (part + ((((size_t)slot_in*64 + b)*32 + g)*NRT)*2);
            float4 x0 = pp[0], x1 = pp[1], x2 = pp[2], x3 = pp[3];
            float S  = x0.x+x0.z + x1.x+x1.z + x2.x+x2.z + x3.x+x3.z;
            float SS = x0.y+x0.w + x1.y+x1.w + x2.y+x2.w + x3.y+x3.w;
            float mu   = S * (1.f/2048.f);
            float var  = SS * (1.f/2048.f) - mu*mu;
            float rstd = rsqrtf(var + 1e-5f);
            float a = gns[tid]*rstd;
            kaf[0][tid] = a;
            kbf[tid] = gnb[tid] - mu*a;
        }
    }
    __syncthreads();

    stage_finish(0);
    if (tid < 384) {
        int c2 = tid & 31;
        int t3 = tid >> 5;
        int rr = t3 % 6;
        int e  = t3 / 6;
        int p  = rr*34 + e*33;
        int au = p*64 + swz8(c2 >> 2, p)*8 + (c2 & 3)*2;
        *(unsigned*)&lds_in[au] = 0u;
    }
    __syncthreads();

    prim_load(1);
    mfma_kc(0);
    stage_finish(1);
    __syncthreads();

    mfma_kc(1);

    const int orow = rt*4 + r0;
#pragma unroll
    for (int mt = 0; mt < 2; ++mt) {
#pragma unroll
        for (int r = 0; r < 4; ++r) {
            int cout = mh*32 + mt*16 + quad*4 + r;
            float bs = bias[cout];
            const float* sp = smap + (size_t)cout*1024 + orow*32;
            u16* op = out + (((size_t)b*64 + cout)*32 + orow)*32;
            float v0 = acc[mt][0][r] + bs + tval*sp[n15];
            float v1 = acc[mt][1][r] + bs + tval*sp[16 + n15];
            op[n15]      = f2h(v0);
            op[16 + n15] = f2h(v1);
            float s = v0 + v1;
            float q = v0*v0 + v1*v1;
            s += __shfl_xor(s, 1); q += __shfl_xor(q, 1);
            s += __shfl_xor(s, 2); q += __shfl_xor(q, 2);
            s += __shfl_xor(s, 4); q += __shfl_xor(q, 4);
            s += __shfl_xor(s, 8); q += __shfl_xor(q, 8);
            if (n15 == 0) { ps[r0*64 + cout] = s; pss[r0*64 + cout] = q; }
        }
    }
    __syncthreads();
    if (tid < 64) {
        rg[tid]  = ps[tid]  + ps[64+tid]  + ps[128+tid]  + ps[192+tid];
        rgq[tid] = pss[tid] + pss[64+tid] + pss[128+tid] + pss[192+tid];
    }
    __syncthreads();
    if (tid < 32) {
        float S  = rg[2*tid]  + rg[2*tid+1];
        float SS = rgq[2*tid] + rgq[2*tid+1];
        float* pp = part + ((((size_t)slot_out*64 + b)*32 + tid)*NRT + rt)*2;
        pp[0] = S; pp[1] = SS;
    }
}

__global__ __launch_bounds__(256) void final_combine16_k(
    const float* __restrict__ ysrc, float* __restrict__ ydst,
    const u16* __restrict__ k0, const u16* __restrict__ k1,
    const u16* __restrict__ k2, const u16* __restrict__ k3,
    const u16* __restrict__ k4, const u16* __restrict__ k5,
    const float* __restrict__ part,
    const float* __restrict__ g2s, const float* __restrict__ g2b,
    float b0, float b1, float b2, float b3, float b4, float b5)
{
    const int bidx = blockIdx.x;
    const int b = bidx >> 6, ch = bidx & 63, g = ch >> 1;
    const int t = threadIdx.x;
    __shared__ float rs[6][2];
    if (t < 12) {
        int jj = t >> 1, st = t & 1;
        const float* pp = part + ((((size_t)(1+jj)*64 + b)*32 + g)*NRT)*2 + st;
        float v = 0.f;
#pragma unroll
        for (int q = 0; q < NRT; ++q) v += pp[2*q];
        rs[jj][st] = v;
    }
    __syncthreads();
    const float bb[6] = {b0, b1, b2, b3, b4, b5};
    float fa[6], fcs = 0.f;
#pragma unroll
    for (int jj = 0; jj < 6; ++jj) {
        float mu   = rs[jj][0] * (1.f/2048.f);
        float var  = rs[jj][1] * (1.f/2048.f) - mu*mu;
        float rstd = rsqrtf(var + 1e-5f);
        float a = g2s[ch]*rstd;
        float c = g2b[ch] - mu*a;
        fa[jj] = bb[jj]*a;
        fcs   += bb[jj]*c;
    }
    const size_t base = ((size_t)bidx*256 + t)*4;
    float4 r = *(const float4*)(ysrc + base);
    r.x += fcs; r.y += fcs; r.z += fcs; r.w += fcs;
    const u16* kp[6] = {k0, k1, k2, k3, k4, k5};
#pragma unroll
    for (int jj = 0; jj < 6; ++jj) {
        ushort4 kv = *(const ushort4*)(kp[jj] + base);
        r.x = fmaf(fa[jj], h2f(kv.x), r.x);
        r.y = fmaf(fa[jj], h2f(kv.y), r.y);
        r.z = fmaf(fa[jj], h2f(kv.z), r.z);
        r.w = fmaf(fa[jj], h2f(kv.w), r.w);
    }
    *(float4*)(ydst + base) = r;
}

// ---------------------------------------------------------------------------

static const double A_[5][5] = {
    {0.161, 0, 0, 0, 0},
    {-0.008480655492356989, 0.335480655492357, 0, 0, 0},
    {2.8971530571054935, -6.359448489975075, 4.3622954328695815, 0, 0},
    {5.325864828439257, -11.748883564062828, 7.4955393428898365, -0.09249506636175525, 0},
    {5.86145544294642, -12.92096931784711, 8.159367898576159, -0.071584973281401, -0.028269050394068383},
};
static const double B_[6] = {
    0.09646076681806523, 0.01, 0.4798896504144996,
    1.379008574103742, -3.290069515436081, 2.324710524099774,
};
static const double C_[5] = {0.161, 0.327, 0.9, 0.9800255409045097, 1.0};

extern "C" void kernel_launch(void* const* d_in, const int* in_sizes, int n_in,
                              void* d_out, int out_size, void* d_ws, size_t ws_size,
                              hipStream_t stream)
{
    const float* x   = (const float*)d_in[0];
    const float* c1w = (const float*)d_in[1];
    const float* c1b = (const float*)d_in[2];
    const float* g1s = (const float*)d_in[3];
    const float* g1b = (const float*)d_in[4];
    const float* c2w = (const float*)d_in[5];
    const float* c2b = (const float*)d_in[6];
    const float* g2s = (const float*)d_in[7];
    const float* g2b = (const float*)d_in[8];

    float* y  = (float*)d_out;
    u16*   wsb = (u16*)d_ws;

    const double dt = 0.125;
    const float dtf = 0.125f;
    const float bw0 = (float)(B_[0]*dt), bw1 = (float)(B_[1]*dt),
                bw2 = (float)(B_[2]*dt), bw3 = (float)(B_[3]*dt),
                bw4 = (float)(B_[4]*dt), bw5 = (float)(B_[5]*dt);
    const dim3 cgrid(NRT, BB);

    // fp32-k layout requirement
    const size_t need32 =
        (size_t)NELEM*2 + (size_t)6*NELEM*4 + (size_t)2*73728*2
      + (size_t)2*65536*4 + (size_t)7*64*32*NRT*2*4 + (size_t)2*NELEM*4;

    if (ws_size >= need32) {
        // ================= fp32-k path (256-thread conv) =================
        u16*   h    = wsb;
        float* kf   = (float*)(wsb + (size_t)NELEM);
        float* k[6];
        for (int i = 0; i < 6; ++i) k[i] = kf + (size_t)i*NELEM;
        u16*   wt1   = (u16*)(kf + (size_t)6*NELEM);
        u16*   wt2   = wt1 + 73728;
        float* smap1 = (float*)(wt2 + 73728);
        float* smap2 = smap1 + 65536;
        float* part  = smap2 + 65536;
        float* YA    = part + (size_t)7*64*32*NRT*2;
        float* YB    = YA + NELEM;
        float* yb[2] = {YA, YB};

        prep_w_k<<<18, 256, 0, stream>>>(c1w, wt1);
        prep_w_k<<<18, 256, 0, stream>>>(c2w, wt2);
        smap_k<<<256, 256, 0, stream>>>(c1w, smap1);
        smap_k<<<256, 256, 0, stream>>>(c2w, smap2);
        hipMemcpyAsync(YA, x, (size_t)NELEM * sizeof(float),
                       hipMemcpyDeviceToDevice, stream);

        for (int s = 0; s < 8; ++s) {
            const float t0 = dtf * (float)s;
            const float* ys = yb[s & 1];

            if (s == 0) {
                conv32_k<0,0,false><<<cgrid, 256, 0, stream>>>(
                    YA, nullptr, nullptr,nullptr,nullptr,nullptr,nullptr,nullptr,
                    nullptr, part, g1s, g1b, g2s, g2b,
                    wt1, smap1, c1b, h, nullptr, t0, 0, 0,
                    0.f,0.f,0.f,0.f,0.f,0.f);
            } else {
                conv32_k<1,6,true><<<cgrid, 256, 0, stream>>>(
                    yb[(s-1)&1], nullptr, k[0],k[1],k[2],k[3],k[4],k[5],
                    yb[s&1], part, g1s, g1b, g2s, g2b,
                    wt1, smap1, c1b, h, nullptr, t0, 0, 0,
                    bw0, bw1, bw2, bw3, bw4, bw5);
            }
            conv32_k<2,0,false><<<cgrid, 256, 0, stream>>>(
                nullptr, h, nullptr,nullptr,nullptr,nullptr,nullptr,nullptr,
                nullptr, part, g1s, g1b, g2s, g2b,
                wt2, smap2, c2b, nullptr, k[0], t0, 0, 1,
                0.f,0.f,0.f,0.f,0.f,0.f);

            for (int j = 1; j < 6; ++j) {
                const float tj = t0 + (float)C_[j-1] * dtf;
                float a[5] = {0,0,0,0,0};
                for (int i = 0; i < j; ++i) a[i] = (float)(A_[j-1][i] * dt);
                switch (j) {
                case 1:
                    conv32_k<1,1,false><<<cgrid, 256, 0, stream>>>(
                        ys, nullptr, k[0],k[1],k[2],k[3],k[4],k[5],
                        nullptr, part, g1s, g1b, g2s, g2b,
                        wt1, smap1, c1b, h, nullptr, tj, 0, 0,
                        a[0],a[1],a[2],a[3],a[4],0.f); break;
                case 2:
                    conv32_k<1,2,false><<<cgrid, 256, 0, stream>>>(
                        ys, nullptr, k[0],k[1],k[2],k[3],k[4],k[5],
                        nullptr, part, g1s, g1b, g2s, g2b,
                        wt1, smap1, c1b, h, nullptr, tj, 0, 0,
                        a[0],a[1],a[2],a[3],a[4],0.f); break;
                case 3:
                    conv32_k<1,3,false><<<cgrid, 256, 0, stream>>>(
                        ys, nullptr, k[0],k[1],k[2],k[3],k[4],k[5],
                        nullptr, part, g1s, g1b, g2s, g2b,
                        wt1, smap1, c1b, h, nullptr, tj, 0, 0,
                        a[0],a[1],a[2],a[3],a[4],0.f); break;
                case 4:
                    conv32_k<1,4,false><<<cgrid, 256, 0, stream>>>(
                        ys, nullptr, k[0],k[1],k[2],k[3],k[4],k[5],
                        nullptr, part, g1s, g1b, g2s, g2b,
                        wt1, smap1, c1b, h, nullptr, tj, 0, 0,
                        a[0],a[1],a[2],a[3],a[4],0.f); break;
                default:
                    conv32_k<1,5,false><<<cgrid, 256, 0, stream>>>(
                        ys, nullptr, k[0],k[1],k[2],k[3],k[4],k[5],
                        nullptr, part, g1s, g1b, g2s, g2b,
                        wt1, smap1, c1b, h, nullptr, tj, 0, 0,
                        a[0],a[1],a[2],a[3],a[4],0.f); break;
                }
                conv32_k<2,0,false><<<cgrid, 256, 0, stream>>>(
                    nullptr, h, nullptr,nullptr,nullptr,nullptr,nullptr,nullptr,
                    nullptr, part, g1s, g1b, g2s, g2b,
                    wt2, smap2, c2b, nullptr, k[j], tj, 0, 1 + j,
                    0.f,0.f,0.f,0.f,0.f,0.f);
            }
        }
        final_combine32_k<<<4096, 256, 0, stream>>>(
            yb[7 & 1], y, k[0], k[1], k[2], k[3], k[4], k[5], part, g2s, g2b,
            bw0, bw1, bw2, bw3, bw4, bw5);
    } else {
        // ================= fallback: round-2 exact (f16 k) =================
        u16*   h  = wsb;
        u16*   k[6];
        for (int i = 0; i < 6; ++i) k[i] = wsb + (size_t)(1 + i) * NELEM;
        u16*   wt1   = wsb + (size_t)7*NELEM;
        u16*   wt2   = wt1 + 73728;
        float* smap1 = (float*)(wt2 + 73728);
        float* smap2 = smap1 + 65536;
        float* part  = smap2 + 65536;
        float* YA    = part + (size_t)7*64*32*NRT*2;
        float* YB    = YA + NELEM;
        float* yb[2] = {YA, YB};

        prep_w_k<<<18, 256, 0, stream>>>(c1w, wt1);
        prep_w_k<<<18, 256, 0, stream>>>(c2w, wt2);
        smap_k<<<256, 256, 0, stream>>>(c1w, smap1);
        smap_k<<<256, 256, 0, stream>>>(c2w, smap2);
        hipMemcpyAsync(YA, x, (size_t)NELEM * sizeof(float),
                       hipMemcpyDeviceToDevice, stream);

        for (int s = 0; s < 8; ++s) {
            const float t0 = dtf * (float)s;
            const float* ys = yb[s & 1];

            if (s == 0) {
                conv16_k<0,0,false><<<cgrid, 512, 0, stream>>>(
                    YA, nullptr, nullptr,nullptr,nullptr,nullptr,nullptr,nullptr,
                    nullptr, part, g1s, g1b, g2s, g2b,
                    wt1, smap1, c1b, h, t0, 0, 0,
                    0.f,0.f,0.f,0.f,0.f,0.f);
            } else {
                conv16_k<1,6,true><<<cgrid, 512, 0, stream>>>(
                    yb[(s-1)&1], nullptr, k[0],k[1],k[2],k[3],k[4],k[5],
                    yb[s&1], part, g1s, g1b, g2s, g2b,
                    wt1, smap1, c1b, h, t0, 0, 0,
                    bw0, bw1, bw2, bw3, bw4, bw5);
            }
            conv16_k<2,0,false><<<cgrid, 512, 0, stream>>>(
                nullptr, h, nullptr,nullptr,nullptr,nullptr,nullptr,nullptr,
                nullptr, part, g1s, g1b, g2s, g2b,
                wt2, smap2, c2b, k[0], t0, 0, 1,
                0.f,0.f,0.f,0.f,0.f,0.f);

            for (int j = 1; j < 6; ++j) {
                const float tj = t0 + (float)C_[j-1] * dtf;
                float a[5] = {0,0,0,0,0};
                for (int i = 0; i < j; ++i) a[i] = (float)(A_[j-1][i] * dt);
                switch (j) {
                case 1:
                    conv16_k<1,1,false><<<cgrid, 512, 0, stream>>>(
                        ys, nullptr, k[0],k[1],k[2],k[3],k[4],k[5],
                        nullptr, part, g1s, g1b, g2s, g2b,
                        wt1, smap1, c1b, h, tj, 0, 0,
                        a[0],a[1],a[2],a[3],a[4],0.f); break;
                case 2:
                    conv16_k<1,2,false><<<cgrid, 512, 0, stream>>>(
                        ys, nullptr, k[0],k[1],k[2],k[3],k[4],k[5],
                        nullptr, part, g1s, g1b, g2s, g2b,
                        wt1, smap1, c1b, h, tj, 0, 0,
                        a[0],a[1],a[2],a[3],a[4],0.f); break;
                case 3:
                    conv16_k<1,3,false><<<cgrid, 512, 0, stream>>>(
                        ys, nullptr, k[0],k[1],k[2],k[3],k[4],k[5],
                        nullptr, part, g1s, g1b, g2s, g2b,
                        wt1, smap1, c1b, h, tj, 0, 0,
                        a[0],a[1],a[2],a[3],a[4],0.f); break;
                case 4:
                    conv16_k<1,4,false><<<cgrid, 512, 0, stream>>>(
                        ys, nullptr, k[0],k[1],k[2],k[3],k[4],k[5],
                        nullptr, part, g1s, g1b, g2s, g2b,
                        wt1, smap1, c1b, h, tj, 0, 0,
                        a[0],a[1],a[2],a[3],a[4],0.f); break;
                default:
                    conv16_k<1,5,false><<<cgrid, 512, 0, stream>>>(
                        ys, nullptr, k[0],k[1],k[2],k[3],k[4],k[5],
                        nullptr, part, g1s, g1b, g2s, g2b,
                        wt1, smap1, c1b, h, tj, 0, 0,
                        a[0],a[1],a[2],a[3],a[4],0.f); break;
                }
                conv16_k<2,0,false><<<cgrid, 512, 0, stream>>>(
                    nullptr, h, nullptr,nullptr,nullptr,nullptr,nullptr,nullptr,
                    nullptr, part, g1s, g1b, g2s, g2b,
                    wt2, smap2, c2b, k[j], tj, 0, 1 + j,
                    0.f,0.f,0.f,0.f,0.f,0.f);
            }
        }
        final_combine16_k<<<4096, 256, 0, stream>>>(
            yb[7 & 1], y, k[0], k[1], k[2], k[3], k[4], k[5], part, g2s, g2b,
            bw0, bw1, bw2, bw3, bw4, bw5);
    }
}

// Round 8
// 1807.011 us; speedup vs baseline: 1.7406x; 1.7406x over previous
//
#include <hip/hip_runtime.h>

typedef __attribute__((ext_vector_type(8))) _Float16 f16x8;
typedef __attribute__((ext_vector_type(4))) float f32x4;
typedef unsigned short u16;

#define BB 64
#define NPIX 1024
#define NELEM (BB*64*NPIX)           // 4194304
#define NRT 8                        // row-tiles of 4 rows

// LDS input layout: [pixel 6*34][chunk-slot swizzled 8x8 u16] (single f16 plane)
#define PLANE (6*34*64)              // 13056 u16

__device__ __forceinline__ int swz8(int c8, int p) {
    return (c8 + ((p + (p >> 2)) & 7)) & 7;
}

__device__ __forceinline__ u16 f2h(float x) {
    _Float16 h = (_Float16)x;
    return __builtin_bit_cast(u16, h);
}
__device__ __forceinline__ float h2f(u16 u) {
    return (float)__builtin_bit_cast(_Float16, u);
}

// ---------------------------------------------------------------------------
__global__ __launch_bounds__(256) void prep_w_k(
    const float* __restrict__ w, u16* __restrict__ wt)
{
    int t = blockIdx.x*256 + threadIdx.x;
    if (t >= 4608) return;
    int lane = t & 63;
    int f = t >> 6;              // 0..71
    int g = f & 7;               // kc*4 + coutblk
    int tap = f >> 3;            // 0..8
    int coutblk = g & 3;
    int kc = g >> 2;
    int cout = coutblk*16 + (lane & 15);
    int quad = lane >> 4;
    u16 v[8];
#pragma unroll
    for (int j = 0; j < 8; ++j) {
        int cin = kc*32 + quad*8 + j;
        v[j] = f2h(w[((size_t)cout*65 + (cin+1))*9 + tap]);
    }
    u16* dst = wt + ((size_t)tap*4096 + (g*64 + lane)*8);
    *(ushort4*)(dst)     = make_ushort4(v[0], v[1], v[2], v[3]);
    *(ushort4*)(dst + 4) = make_ushort4(v[4], v[5], v[6], v[7]);
}

__global__ __launch_bounds__(256) void smap_k(
    const float* __restrict__ w, float* __restrict__ smap)
{
    int t = blockIdx.x*256 + threadIdx.x;
    int cout = t >> 10;
    int pix = t & 1023;
    int y = pix >> 5, x = pix & 31;
    float s = 0.f;
#pragma unroll
    for (int dy = 0; dy < 3; ++dy)
#pragma unroll
        for (int dx = 0; dx < 3; ++dx) {
            int yy = y + dy - 1, xx = x + dx - 1;
            if ((unsigned)yy < 32u && (unsigned)xx < 32u)
                s += w[(size_t)cout*65*9 + dy*3 + dx];
        }
    smap[t] = s;
}

// ---------------------------------------------------------------------------
// Fused conv3x3 (single fp16 MFMA), kc-split pipelined staging.
//  MODE 0: v = src0 (fp32, raw)
//  MODE 1: v = src0 + kbf[ch] + sum_{jj<NK} kaf[jj][ch]*h2f(k_jj)
//          (WRITEY: also store v as fp32 to yout, interior rows only)
//  MODE 2: v = relu(kaf[0][ch]*h2f(srcb) + kbf[ch])
// ---------------------------------------------------------------------------
template<int MODE, int NK, bool WRITEY>
__global__ __launch_bounds__(512, 4) void conv_mfma_k(
    const float* __restrict__ src0, const u16* __restrict__ srcb,
    const u16* __restrict__ kp0, const u16* __restrict__ kp1,
    const u16* __restrict__ kp2, const u16* __restrict__ kp3,
    const u16* __restrict__ kp4, const u16* __restrict__ kp5,
    float* __restrict__ yout,
    float* __restrict__ part,
    const float* __restrict__ gns, const float* __restrict__ gnb,
    const float* __restrict__ gks, const float* __restrict__ gkb,
    const u16* __restrict__ wt, const float* __restrict__ smap,
    const float* __restrict__ bias, u16* __restrict__ out, float tval,
    int slot_in, int slot_out,
    float a1, float a2, float a3, float a4, float a5, float a6)
{
    __shared__ u16 lds_in[PLANE];            // 26112 B
    __shared__ float kaf[6][64];
    __shared__ float kbf[64];
    __shared__ float ps[256], pss[256];      // [row4][cout64]
    __shared__ float rg[64], rgq[64];

    const int rt  = blockIdx.x;              // 0..7
    const int b   = blockIdx.y;
    const int tid = threadIdx.x;
    const int wv   = tid >> 6;               // 0..7
    const int lane = tid & 63;
    const int quad = lane >> 4;
    const int n15  = lane & 15;
    const int r0   = wv & 3;                 // row in tile
    const int mh   = wv >> 2;                // cout half

    float4 Y0[2], Y1[2];
    ushort4 H0[2], H1[2];

    // ---- primary loads for half h: units [h*768, h*768+768) ----
    auto prim_load = [&](int hh) {
#pragma unroll
        for (int uu = 0; uu < 2; ++uu) {
            int ur = tid + uu*512;
            if (ur >= 768) continue;
            int u = hh*768 + ur;
            int q4 = u & 7;
            int t2 = u >> 3;
            int rr = t2 % 6;
            int c2 = t2 / 6;
            int gr = rt*4 + rr - 1;
            if ((unsigned)gr < 32u) {
                const size_t base = (((size_t)b*64 + c2*2)*32 + gr)*32 + q4*4;
                if constexpr (MODE == 2) {
                    H0[uu] = *(const ushort4*)(srcb + base);
                    H1[uu] = *(const ushort4*)(srcb + base + 1024);
                } else {
                    Y0[uu] = *(const float4*)(src0 + base);
                    Y1[uu] = *(const float4*)(src0 + base + 1024);
                }
            }
        }
    };

    // ---- combine + LDS write for half h ----
    auto stage_finish = [&](int hh) {
#pragma unroll
        for (int uu = 0; uu < 2; ++uu) {
            int ur = tid + uu*512;
            if (ur >= 768) continue;
            int u = hh*768 + ur;
            int q4 = u & 7;
            int t2 = u >> 3;
            int rr = t2 % 6;
            int c2 = t2 / 6;
            int gr = rt*4 + rr - 1;
            bool ok = (unsigned)gr < 32u;
            int ch0 = c2*2, ch1 = ch0 + 1;
            float4 a0 = make_float4(0.f,0.f,0.f,0.f), a1v = a0;
            if (ok) {
                const size_t base = (((size_t)b*64 + ch0)*32 + gr)*32 + q4*4;
                if constexpr (MODE == 2) {
                    float A0 = kaf[0][ch0], B0 = kbf[ch0];
                    float A1 = kaf[0][ch1], B1 = kbf[ch1];
                    a0.x = fmaxf(fmaf(h2f(H0[uu].x),A0,B0), 0.f);
                    a0.y = fmaxf(fmaf(h2f(H0[uu].y),A0,B0), 0.f);
                    a0.z = fmaxf(fmaf(h2f(H0[uu].z),A0,B0), 0.f);
                    a0.w = fmaxf(fmaf(h2f(H0[uu].w),A0,B0), 0.f);
                    a1v.x = fmaxf(fmaf(h2f(H1[uu].x),A1,B1), 0.f);
                    a1v.y = fmaxf(fmaf(h2f(H1[uu].y),A1,B1), 0.f);
                    a1v.z = fmaxf(fmaf(h2f(H1[uu].z),A1,B1), 0.f);
                    a1v.w = fmaxf(fmaf(h2f(H1[uu].w),A1,B1), 0.f);
                } else {
                    a0 = Y0[uu]; a1v = Y1[uu];
                    if constexpr (MODE == 1) {
                        float f0 = kbf[ch0], f1 = kbf[ch1];
                        a0.x += f0; a0.y += f0; a0.z += f0; a0.w += f0;
                        a1v.x += f1; a1v.y += f1; a1v.z += f1; a1v.w += f1;
                        const u16* kps[6] = {kp0, kp1, kp2, kp3, kp4, kp5};
#pragma unroll
                        for (int jj = 0; jj < NK; ++jj) {
                            ushort4 kv0 = *(const ushort4*)(kps[jj] + base);
                            ushort4 kv1 = *(const ushort4*)(kps[jj] + base + 1024);
                            float fa0 = kaf[jj][ch0], fa1 = kaf[jj][ch1];
                            a0.x = fmaf(fa0, h2f(kv0.x), a0.x);
                            a0.y = fmaf(fa0, h2f(kv0.y), a0.y);
                            a0.z = fmaf(fa0, h2f(kv0.z), a0.z);
                            a0.w = fmaf(fa0, h2f(kv0.w), a0.w);
                            a1v.x = fmaf(fa1, h2f(kv1.x), a1v.x);
                            a1v.y = fmaf(fa1, h2f(kv1.y), a1v.y);
                            a1v.z = fmaf(fa1, h2f(kv1.z), a1v.z);
                            a1v.w = fmaf(fa1, h2f(kv1.w), a1v.w);
                        }
                    }
                }
                if constexpr (WRITEY) {
                    if (rr >= 1 && rr <= 4) {
                        *(float4*)(yout + base)        = a0;
                        *(float4*)(yout + base + 1024) = a1v;
                    }
                }
            }
            float v0[4] = {a0.x, a0.y, a0.z, a0.w};
            float v1[4] = {a1v.x, a1v.y, a1v.z, a1v.w};
            int c8 = c2 >> 2, cl = c2 & 3;
            int pbase = rr*34 + 1 + q4*4;
#pragma unroll
            for (int j = 0; j < 4; ++j) {
                int p = pbase + j;
                int au = p*64 + swz8(c8, p)*8 + cl*2;
                *(unsigned*)&lds_in[au] =
                    (unsigned)f2h(v0[j]) | ((unsigned)f2h(v1[j]) << 16);
            }
        }
    };

    f32x4 acc[2][2] = {};
    auto mfma_kc = [&](int kc) {
#pragma unroll 3
        for (int tap = 0; tap < 9; ++tap) {
            const int dy = tap / 3;
            const int dx = tap - dy*3;
            const int rowoff = (r0 + dy)*34 + dx;
            const u16* wtap = wt + (size_t)tap*4096;
            f16x8 A[2], Bf[2];
#pragma unroll
            for (int mt = 0; mt < 2; ++mt)
                A[mt] = *(const f16x8*)
                    &wtap[((kc*4 + mh*2 + mt)*64 + lane)*8];
#pragma unroll
            for (int nt = 0; nt < 2; ++nt) {
                int p = rowoff + nt*16 + n15;
                Bf[nt] = *(const f16x8*)&lds_in[p*64 + swz8(kc*4 + quad, p)*8];
            }
#pragma unroll
            for (int mt = 0; mt < 2; ++mt)
#pragma unroll
                for (int nt = 0; nt < 2; ++nt)
                    acc[mt][nt] = __builtin_amdgcn_mfma_f32_16x16x32_f16(
                        A[mt], Bf[nt], acc[mt][nt], 0, 0, 0);
        }
    };

    // ==== phase 0: issue half-0 primary loads, compute GN coefficients ====
    prim_load(0);

    if constexpr (MODE == 1) {
        if (tid < 64) {
            const float aa[6] = {a1, a2, a3, a4, a5, a6};
            int g = tid >> 1;
            float acb = 0.f;
#pragma unroll
            for (int jj = 0; jj < NK; ++jj) {
                const float4* pp = (const float4*)
                    (part + ((((size_t)(1+jj)*64 + b)*32 + g)*NRT)*2);
                float4 x0 = pp[0], x1 = pp[1], x2 = pp[2], x3 = pp[3];
                float S  = x0.x+x0.z + x1.x+x1.z + x2.x+x2.z + x3.x+x3.z;
                float SS = x0.y+x0.w + x1.y+x1.w + x2.y+x2.w + x3.y+x3.w;
                float mu   = S * (1.f/2048.f);
                float var  = SS * (1.f/2048.f) - mu*mu;
                float rstd = rsqrtf(var + 1e-5f);
                float a = gks[tid]*rstd;
                float c = gkb[tid] - mu*a;
                kaf[jj][tid] = aa[jj]*a;
                acb += aa[jj]*c;
            }
            kbf[tid] = acb;
        }
    } else if constexpr (MODE == 2) {
        if (tid < 64) {
            int g = tid >> 1;
            const float4* pp = (const float4*)
                (part + ((((size_t)slot_in*64 + b)*32 + g)*NRT)*2);
            float4 x0 = pp[0], x1 = pp[1], x2 = pp[2], x3 = pp[3];
            float S  = x0.x+x0.z + x1.x+x1.z + x2.x+x2.z + x3.x+x3.z;
            float SS = x0.y+x0.w + x1.y+x1.w + x2.y+x2.w + x3.y+x3.w;
            float mu   = S * (1.f/2048.f);
            float var  = SS * (1.f/2048.f) - mu*mu;
            float rstd = rsqrtf(var + 1e-5f);
            float a = gns[tid]*rstd;
            kaf[0][tid] = a;
            kbf[tid] = gnb[tid] - mu*a;
        }
    }
    __syncthreads();                 // kaf/kbf ready

    // ==== phase 1: finish half-0 staging + halo zero ====
    stage_finish(0);
    if (tid < 384) {
        int c2 = tid & 31;
        int t3 = tid >> 5;           // 0..11
        int rr = t3 % 6;
        int e  = t3 / 6;             // 0..1
        int p  = rr*34 + e*33;
        int au = p*64 + swz8(c2 >> 2, p)*8 + (c2 & 3)*2;
        *(unsigned*)&lds_in[au] = 0u;
    }
    __syncthreads();                 // kc0 plane + halos ready

    // ==== phase 2: half-1 loads in flight under kc0 MFMA ====
    prim_load(1);
    mfma_kc(0);
    stage_finish(1);
    __syncthreads();                 // kc1 plane ready

    // ==== phase 3 ====
    mfma_kc(1);

    // ---- epilogue: write f16 out + per-block GN partials ----
    const int orow = rt*4 + r0;
#pragma unroll
    for (int mt = 0; mt < 2; ++mt) {
#pragma unroll
        for (int r = 0; r < 4; ++r) {
            int cout = mh*32 + mt*16 + quad*4 + r;
            float bs = bias[cout];
            const float* sp = smap + (size_t)cout*1024 + orow*32;
            u16* op = out + (((size_t)b*64 + cout)*32 + orow)*32;
            float v0 = acc[mt][0][r] + bs + tval*sp[n15];
            float v1 = acc[mt][1][r] + bs + tval*sp[16 + n15];
            op[n15]      = f2h(v0);
            op[16 + n15] = f2h(v1);
            float s = v0 + v1;
            float q = v0*v0 + v1*v1;
            s += __shfl_xor(s, 1); q += __shfl_xor(q, 1);
            s += __shfl_xor(s, 2); q += __shfl_xor(q, 2);
            s += __shfl_xor(s, 4); q += __shfl_xor(q, 4);
            s += __shfl_xor(s, 8); q += __shfl_xor(q, 8);
            if (n15 == 0) { ps[r0*64 + cout] = s; pss[r0*64 + cout] = q; }
        }
    }
    __syncthreads();
    if (tid < 64) {
        rg[tid]  = ps[tid]  + ps[64+tid]  + ps[128+tid]  + ps[192+tid];
        rgq[tid] = pss[tid] + pss[64+tid] + pss[128+tid] + pss[192+tid];
    }
    __syncthreads();
    if (tid < 32) {
        float S  = rg[2*tid]  + rg[2*tid+1];
        float SS = rgq[2*tid] + rgq[2*tid+1];
        float* pp = part + ((((size_t)slot_out*64 + b)*32 + tid)*NRT + rt)*2;
        pp[0] = S; pp[1] = SS;
    }
}

// ---------------------------------------------------------------------------
// Final combine (last step only): ydst = ysrc + sum_j (B_j*dt)*gn2affine(k_j).
// ---------------------------------------------------------------------------
__global__ __launch_bounds__(256) void final_combine_k(
    const float* __restrict__ ysrc, float* __restrict__ ydst,
    const u16* __restrict__ k0, const u16* __restrict__ k1,
    const u16* __restrict__ k2, const u16* __restrict__ k3,
    const u16* __restrict__ k4, const u16* __restrict__ k5,
    const float* __restrict__ part,
    const float* __restrict__ g2s, const float* __restrict__ g2b,
    float b0, float b1, float b2, float b3, float b4, float b5)
{
    const int bidx = blockIdx.x;
    const int b = bidx >> 6, ch = bidx & 63, g = ch >> 1;
    const int t = threadIdx.x;
    __shared__ float rs[6][2];
    if (t < 12) {
        int jj = t >> 1, st = t & 1;
        const float* pp = part + ((((size_t)(1+jj)*64 + b)*32 + g)*NRT)*2 + st;
        float v = 0.f;
#pragma unroll
        for (int q = 0; q < NRT; ++q) v += pp[2*q];
        rs[jj][st] = v;
    }
    __syncthreads();
    const float bb[6] = {b0, b1, b2, b3, b4, b5};
    float fa[6], fcs = 0.f;
#pragma unroll
    for (int jj = 0; jj < 6; ++jj) {
        float mu   = rs[jj][0] * (1.f/2048.f);
        float var  = rs[jj][1] * (1.f/2048.f) - mu*mu;
        float rstd = rsqrtf(var + 1e-5f);
        float a = g2s[ch]*rstd;
        float c = g2b[ch] - mu*a;
        fa[jj] = bb[jj]*a;
        fcs   += bb[jj]*c;
    }
    const size_t base = ((size_t)bidx*256 + t)*4;
    float4 r = *(const float4*)(ysrc + base);
    r.x += fcs; r.y += fcs; r.z += fcs; r.w += fcs;
    const u16* kp[6] = {k0, k1, k2, k3, k4, k5};
#pragma unroll
    for (int jj = 0; jj < 6; ++jj) {
        ushort4 kv = *(const ushort4*)(kp[jj] + base);
        r.x = fmaf(fa[jj], h2f(kv.x), r.x);
        r.y = fmaf(fa[jj], h2f(kv.y), r.y);
        r.z = fmaf(fa[jj], h2f(kv.z), r.z);
        r.w = fmaf(fa[jj], h2f(kv.w), r.w);
    }
    *(float4*)(ydst + base) = r;
}

// ---------------------------------------------------------------------------

static const double A_[5][5] = {
    {0.161, 0, 0, 0, 0},
    {-0.008480655492356989, 0.335480655492357, 0, 0, 0},
    {2.8971530571054935, -6.359448489975075, 4.3622954328695815, 0, 0},
    {5.325864828439257, -11.748883564062828, 7.4955393428898365, -0.09249506636175525, 0},
    {5.86145544294642, -12.92096931784711, 8.159367898576159, -0.071584973281401, -0.028269050394068383},
};
static const double B_[6] = {
    0.09646076681806523, 0.01, 0.4798896504144996,
    1.379008574103742, -3.290069515436081, 2.324710524099774,
};
static const double C_[5] = {0.161, 0.327, 0.9, 0.9800255409045097, 1.0};

extern "C" void kernel_launch(void* const* d_in, const int* in_sizes, int n_in,
                              void* d_out, int out_size, void* d_ws, size_t ws_size,
                              hipStream_t stream)
{
    const float* x   = (const float*)d_in[0];
    const float* c1w = (const float*)d_in[1];
    const float* c1b = (const float*)d_in[2];
    const float* g1s = (const float*)d_in[3];
    const float* g1b = (const float*)d_in[4];
    const float* c2w = (const float*)d_in[5];
    const float* c2b = (const float*)d_in[6];
    const float* g2s = (const float*)d_in[7];
    const float* g2b = (const float*)d_in[8];

    float* y  = (float*)d_out;
    u16*   wsb = (u16*)d_ws;
    u16*   h  = wsb;
    u16*   k[6];
    for (int i = 0; i < 6; ++i) k[i] = wsb + (size_t)(1 + i) * NELEM;
    u16*   wt1   = wsb + (size_t)7*NELEM;
    u16*   wt2   = wt1 + 73728;
    float* smap1 = (float*)(wt2 + 73728);
    float* smap2 = smap1 + 65536;
    float* part  = smap2 + 65536;    // 7*64*32*8*2 floats
    float* YA    = part + (size_t)7*64*32*8*2;
    float* YB    = YA + NELEM;
    float* yb[2] = {YA, YB};

    const double dt = 0.125;
    const float dtf = 0.125f;

    prep_w_k<<<18, 256, 0, stream>>>(c1w, wt1);
    prep_w_k<<<18, 256, 0, stream>>>(c2w, wt2);
    smap_k<<<256, 256, 0, stream>>>(c1w, smap1);
    smap_k<<<256, 256, 0, stream>>>(c2w, smap2);

    hipMemcpyAsync(YA, x, (size_t)NELEM * sizeof(float),
                   hipMemcpyDeviceToDevice, stream);

    const dim3 cgrid(NRT, BB);
    const float bw0 = (float)(B_[0]*dt), bw1 = (float)(B_[1]*dt),
                bw2 = (float)(B_[2]*dt), bw3 = (float)(B_[3]*dt),
                bw4 = (float)(B_[4]*dt), bw5 = (float)(B_[5]*dt);

    for (int s = 0; s < 8; ++s) {
        const float t0 = dtf * (float)s;
        const float* ys = yb[s & 1];

        // ---- stage 0 conv1 ----
        if (s == 0) {
            conv_mfma_k<0,0,false><<<cgrid, 512, 0, stream>>>(
                YA, nullptr, nullptr,nullptr,nullptr,nullptr,nullptr,nullptr,
                nullptr, part, g1s, g1b, g2s, g2b,
                wt1, smap1, c1b, h, t0, 0, 0,
                0.f,0.f,0.f,0.f,0.f,0.f);
        } else {
            // fused: y_s = y_{s-1} + sum_j (B_j*dt)*gn2(k_j^{s-1}); stage+write
            conv_mfma_k<1,6,true><<<cgrid, 512, 0, stream>>>(
                yb[(s-1)&1], nullptr, k[0],k[1],k[2],k[3],k[4],k[5],
                yb[s&1], part, g1s, g1b, g2s, g2b,
                wt1, smap1, c1b, h, t0, 0, 0,
                bw0, bw1, bw2, bw3, bw4, bw5);
        }
        conv_mfma_k<2,0,false><<<cgrid, 512, 0, stream>>>(
            nullptr, h, nullptr,nullptr,nullptr,nullptr,nullptr,nullptr,
            nullptr, part, g1s, g1b, g2s, g2b,
            wt2, smap2, c2b, k[0], t0, 0, 1,
            0.f,0.f,0.f,0.f,0.f,0.f);

        // ---- stages 1..5 ----
        for (int j = 1; j < 6; ++j) {
            const float tj = t0 + (float)C_[j-1] * dtf;
            float a[5] = {0,0,0,0,0};
            for (int i = 0; i < j; ++i) a[i] = (float)(A_[j-1][i] * dt);
            switch (j) {
            case 1:
                conv_mfma_k<1,1,false><<<cgrid, 512, 0, stream>>>(
                    ys, nullptr, k[0],k[1],k[2],k[3],k[4],k[5],
                    nullptr, part, g1s, g1b, g2s, g2b,
                    wt1, smap1, c1b, h, tj, 0, 0,
                    a[0],a[1],a[2],a[3],a[4],0.f); break;
            case 2:
                conv_mfma_k<1,2,false><<<cgrid, 512, 0, stream>>>(
                    ys, nullptr, k[0],k[1],k[2],k[3],k[4],k[5],
                    nullptr, part, g1s, g1b, g2s, g2b,
                    wt1, smap1, c1b, h, tj, 0, 0,
                    a[0],a[1],a[2],a[3],a[4],0.f); break;
            case 3:
                conv_mfma_k<1,3,false><<<cgrid, 512, 0, stream>>>(
                    ys, nullptr, k[0],k[1],k[2],k[3],k[4],k[5],
                    nullptr, part, g1s, g1b, g2s, g2b,
                    wt1, smap1, c1b, h, tj, 0, 0,
                    a[0],a[1],a[2],a[3],a[4],0.f); break;
            case 4:
                conv_mfma_k<1,4,false><<<cgrid, 512, 0, stream>>>(
                    ys, nullptr, k[0],k[1],k[2],k[3],k[4],k[5],
                    nullptr, part, g1s, g1b, g2s, g2b,
                    wt1, smap1, c1b, h, tj, 0, 0,
                    a[0],a[1],a[2],a[3],a[4],0.f); break;
            default:
                conv_mfma_k<1,5,false><<<cgrid, 512, 0, stream>>>(
                    ys, nullptr, k[0],k[1],k[2],k[3],k[4],k[5],
                    nullptr, part, g1s, g1b, g2s, g2b,
                    wt1, smap1, c1b, h, tj, 0, 0,
                    a[0],a[1],a[2],a[3],a[4],0.f); break;
            }
            conv_mfma_k<2,0,false><<<cgrid, 512, 0, stream>>>(
                nullptr, h, nullptr,nullptr,nullptr,nullptr,nullptr,nullptr,
                nullptr, part, g1s, g1b, g2s, g2b,
                wt2, smap2, c2b, k[j], tj, 0, 1 + j,
                0.f,0.f,0.f,0.f,0.f,0.f);
        }
    }
    // last step's combine -> d_out
    final_combine_k<<<4096, 256, 0, stream>>>(
        yb[7 & 1], y, k[0], k[1], k[2], k[3], k[4], k[5], part, g2s, g2b,
        bw0, bw1, bw2, bw3, bw4, bw5);
}

// Round 10
// 1774.111 us; speedup vs baseline: 1.7729x; 1.0185x over previous
//
#include <hip/hip_runtime.h>

typedef __attribute__((ext_vector_type(8))) _Float16 f16x8;
typedef __attribute__((ext_vector_type(4))) float f32x4;
typedef unsigned short u16;

#define BB 64
#define NPIX 1024
#define NELEM (BB*64*NPIX)           // 4194304
#define NRT 8                        // row-tiles of 4 rows

// LDS input layout: [pixel 6*34][chunk-slot swizzled 8x8 u16] (single f16 plane)
#define PLANE (6*34*64)              // 13056 u16

__device__ __forceinline__ int swz8(int c8, int p) {
    return (c8 + ((p + (p >> 2)) & 7)) & 7;
}

__device__ __forceinline__ u16 f2h(float x) {
    _Float16 h = (_Float16)x;
    return __builtin_bit_cast(u16, h);
}
__device__ __forceinline__ float h2f(u16 u) {
    return (float)__builtin_bit_cast(_Float16, u);
}

// ---------------------------------------------------------------------------
__global__ __launch_bounds__(256) void prep_w_k(
    const float* __restrict__ w, u16* __restrict__ wt)
{
    int t = blockIdx.x*256 + threadIdx.x;
    if (t >= 4608) return;
    int lane = t & 63;
    int f = t >> 6;              // 0..71
    int g = f & 7;               // kc*4 + coutblk
    int tap = f >> 3;            // 0..8
    int coutblk = g & 3;
    int kc = g >> 2;
    int cout = coutblk*16 + (lane & 15);
    int quad = lane >> 4;
    u16 v[8];
#pragma unroll
    for (int j = 0; j < 8; ++j) {
        int cin = kc*32 + quad*8 + j;
        v[j] = f2h(w[((size_t)cout*65 + (cin+1))*9 + tap]);
    }
    u16* dst = wt + ((size_t)tap*4096 + (g*64 + lane)*8);
    *(ushort4*)(dst)     = make_ushort4(v[0], v[1], v[2], v[3]);
    *(ushort4*)(dst + 4) = make_ushort4(v[4], v[5], v[6], v[7]);
}

__global__ __launch_bounds__(256) void smap_k(
    const float* __restrict__ w, float* __restrict__ smap)
{
    int t = blockIdx.x*256 + threadIdx.x;
    int cout = t >> 10;
    int pix = t & 1023;
    int y = pix >> 5, x = pix & 31;
    float s = 0.f;
#pragma unroll
    for (int dy = 0; dy < 3; ++dy)
#pragma unroll
        for (int dx = 0; dx < 3; ++dx) {
            int yy = y + dy - 1, xx = x + dx - 1;
            if ((unsigned)yy < 32u && (unsigned)xx < 32u)
                s += w[(size_t)cout*65*9 + dy*3 + dx];
        }
    smap[t] = s;
}

// ---------------------------------------------------------------------------
// Fused conv3x3 (single fp16 MFMA), kc-split pipelined staging.
//  MODE 0: v = src0 (fp32, raw)
//  MODE 1: v = src0 + kbf[ch] + sum_{jj<NK} kaf[jj][ch]*h2f(k_jj)
//          (WRITEY: also store v as fp32 to yout, interior rows only)
//  MODE 2: v = relu(kaf[0][ch]*h2f(srcb) + kbf[ch])
// ---------------------------------------------------------------------------
template<int MODE, int NK, bool WRITEY>
__global__ __launch_bounds__(512, 4) void conv_mfma_k(
    const float* __restrict__ src0, const u16* __restrict__ srcb,
    const u16* __restrict__ kp0, const u16* __restrict__ kp1,
    const u16* __restrict__ kp2, const u16* __restrict__ kp3,
    const u16* __restrict__ kp4, const u16* __restrict__ kp5,
    float* __restrict__ yout,
    float* __restrict__ part,
    const float* __restrict__ gns, const float* __restrict__ gnb,
    const float* __restrict__ gks, const float* __restrict__ gkb,
    const u16* __restrict__ wt, const float* __restrict__ smap,
    const float* __restrict__ bias, u16* __restrict__ out, float tval,
    int slot_in, int slot_out,
    float a1, float a2, float a3, float a4, float a5, float a6)
{
    __shared__ u16 lds_in[PLANE];            // 26112 B
    __shared__ float kaf[6][64];
    __shared__ float kbf[64];
    __shared__ float ps[256], pss[256];      // [row4][cout64]
    __shared__ float rg[64], rgq[64];

    const int rt  = blockIdx.x;              // 0..7
    const int b   = blockIdx.y;
    const int tid = threadIdx.x;
    const int wv   = tid >> 6;               // 0..7
    const int lane = tid & 63;
    const int quad = lane >> 4;
    const int n15  = lane & 15;
    const int r0   = wv & 3;                 // row in tile
    const int mh   = wv >> 2;                // cout half

    float4 Y0[2], Y1[2];
    ushort4 H0[2], H1[2];

    // ---- primary loads for half h: units [h*768, h*768+768) ----
    auto prim_load = [&](int hh) {
#pragma unroll
        for (int uu = 0; uu < 2; ++uu) {
            int ur = tid + uu*512;
            if (ur >= 768) continue;
            int u = hh*768 + ur;
            int q4 = u & 7;
            int t2 = u >> 3;
            int rr = t2 % 6;
            int c2 = t2 / 6;
            int gr = rt*4 + rr - 1;
            if ((unsigned)gr < 32u) {
                const size_t base = (((size_t)b*64 + c2*2)*32 + gr)*32 + q4*4;
                if constexpr (MODE == 2) {
                    H0[uu] = *(const ushort4*)(srcb + base);
                    H1[uu] = *(const ushort4*)(srcb + base + 1024);
                } else {
                    Y0[uu] = *(const float4*)(src0 + base);
                    Y1[uu] = *(const float4*)(src0 + base + 1024);
                }
            }
        }
    };

    // ---- combine + LDS write for half h ----
    auto stage_finish = [&](int hh) {
#pragma unroll
        for (int uu = 0; uu < 2; ++uu) {
            int ur = tid + uu*512;
            if (ur >= 768) continue;
            int u = hh*768 + ur;
            int q4 = u & 7;
            int t2 = u >> 3;
            int rr = t2 % 6;
            int c2 = t2 / 6;
            int gr = rt*4 + rr - 1;
            bool ok = (unsigned)gr < 32u;
            int ch0 = c2*2, ch1 = ch0 + 1;
            float4 a0 = make_float4(0.f,0.f,0.f,0.f), a1v = a0;
            if (ok) {
                const size_t base = (((size_t)b*64 + ch0)*32 + gr)*32 + q4*4;
                if constexpr (MODE == 2) {
                    float A0 = kaf[0][ch0], B0 = kbf[ch0];
                    float A1 = kaf[0][ch1], B1 = kbf[ch1];
                    a0.x = fmaxf(fmaf(h2f(H0[uu].x),A0,B0), 0.f);
                    a0.y = fmaxf(fmaf(h2f(H0[uu].y),A0,B0), 0.f);
                    a0.z = fmaxf(fmaf(h2f(H0[uu].z),A0,B0), 0.f);
                    a0.w = fmaxf(fmaf(h2f(H0[uu].w),A0,B0), 0.f);
                    a1v.x = fmaxf(fmaf(h2f(H1[uu].x),A1,B1), 0.f);
                    a1v.y = fmaxf(fmaf(h2f(H1[uu].y),A1,B1), 0.f);
                    a1v.z = fmaxf(fmaf(h2f(H1[uu].z),A1,B1), 0.f);
                    a1v.w = fmaxf(fmaf(h2f(H1[uu].w),A1,B1), 0.f);
                } else {
                    a0 = Y0[uu]; a1v = Y1[uu];
                    if constexpr (MODE == 1) {
                        float f0 = kbf[ch0], f1 = kbf[ch1];
                        a0.x += f0; a0.y += f0; a0.z += f0; a0.w += f0;
                        a1v.x += f1; a1v.y += f1; a1v.z += f1; a1v.w += f1;
                        const u16* kps[6] = {kp0, kp1, kp2, kp3, kp4, kp5};
#pragma unroll
                        for (int jj = 0; jj < NK; ++jj) {
                            ushort4 kv0 = *(const ushort4*)(kps[jj] + base);
                            ushort4 kv1 = *(const ushort4*)(kps[jj] + base + 1024);
                            float fa0 = kaf[jj][ch0], fa1 = kaf[jj][ch1];
                            a0.x = fmaf(fa0, h2f(kv0.x), a0.x);
                            a0.y = fmaf(fa0, h2f(kv0.y), a0.y);
                            a0.z = fmaf(fa0, h2f(kv0.z), a0.z);
                            a0.w = fmaf(fa0, h2f(kv0.w), a0.w);
                            a1v.x = fmaf(fa1, h2f(kv1.x), a1v.x);
                            a1v.y = fmaf(fa1, h2f(kv1.y), a1v.y);
                            a1v.z = fmaf(fa1, h2f(kv1.z), a1v.z);
                            a1v.w = fmaf(fa1, h2f(kv1.w), a1v.w);
                        }
                    }
                }
                if constexpr (WRITEY) {
                    if (rr >= 1 && rr <= 4) {
                        *(float4*)(yout + base)        = a0;
                        *(float4*)(yout + base + 1024) = a1v;
                    }
                }
            }
            float v0[4] = {a0.x, a0.y, a0.z, a0.w};
            float v1[4] = {a1v.x, a1v.y, a1v.z, a1v.w};
            int c8 = c2 >> 2, cl = c2 & 3;
            int pbase = rr*34 + 1 + q4*4;
#pragma unroll
            for (int j = 0; j < 4; ++j) {
                int p = pbase + j;
                int au = p*64 + swz8(c8, p)*8 + cl*2;
                *(unsigned*)&lds_in[au] =
                    (unsigned)f2h(v0[j]) | ((unsigned)f2h(v1[j]) << 16);
            }
        }
    };

    f32x4 acc[2][2] = {};
    auto mfma_kc = [&](int kc) {
#pragma unroll 3
        for (int tap = 0; tap < 9; ++tap) {
            const int dy = tap / 3;
            const int dx = tap - dy*3;
            const int rowoff = (r0 + dy)*34 + dx;
            const u16* wtap = wt + (size_t)tap*4096;
            f16x8 A[2], Bf[2];
#pragma unroll
            for (int mt = 0; mt < 2; ++mt)
                A[mt] = *(const f16x8*)
                    &wtap[((kc*4 + mh*2 + mt)*64 + lane)*8];
#pragma unroll
            for (int nt = 0; nt < 2; ++nt) {
                int p = rowoff + nt*16 + n15;
                Bf[nt] = *(const f16x8*)&lds_in[p*64 + swz8(kc*4 + quad, p)*8];
            }
#pragma unroll
            for (int mt = 0; mt < 2; ++mt)
#pragma unroll
                for (int nt = 0; nt < 2; ++nt)
                    acc[mt][nt] = __builtin_amdgcn_mfma_f32_16x16x32_f16(
                        A[mt], Bf[nt], acc[mt][nt], 0, 0, 0);
        }
    };

    // ==== phase 0: issue half-0 primary loads, compute GN coefficients ====
    prim_load(0);

    if constexpr (MODE == 1) {
        if (tid < 64) {
            const float aa[6] = {a1, a2, a3, a4, a5, a6};
            int g = tid >> 1;
            float acb = 0.f;
#pragma unroll
            for (int jj = 0; jj < NK; ++jj) {
                const float4* pp = (const float4*)
                    (part + ((((size_t)(1+jj)*64 + b)*32 + g)*NRT)*2);
                float4 x0 = pp[0], x1 = pp[1], x2 = pp[2], x3 = pp[3];
                float S  = x0.x+x0.z + x1.x+x1.z + x2.x+x2.z + x3.x+x3.z;
                float SS = x0.y+x0.w + x1.y+x1.w + x2.y+x2.w + x3.y+x3.w;
                float mu   = S * (1.f/2048.f);
                float var  = SS * (1.f/2048.f) - mu*mu;
                float rstd = rsqrtf(var + 1e-5f);
                float a = gks[tid]*rstd;
                float c = gkb[tid] - mu*a;
                kaf[jj][tid] = aa[jj]*a;
                acb += aa[jj]*c;
            }
            kbf[tid] = acb;
        }
    } else if constexpr (MODE == 2) {
        if (tid < 64) {
            int g = tid >> 1;
            const float4* pp = (const float4*)
                (part + ((((size_t)slot_in*64 + b)*32 + g)*NRT)*2);
            float4 x0 = pp[0], x1 = pp[1], x2 = pp[2], x3 = pp[3];
            float S  = x0.x+x0.z + x1.x+x1.z + x2.x+x2.z + x3.x+x3.z;
            float SS = x0.y+x0.w + x1.y+x1.w + x2.y+x2.w + x3.y+x3.w;
            float mu   = S * (1.f/2048.f);
            float var  = SS * (1.f/2048.f) - mu*mu;
            float rstd = rsqrtf(var + 1e-5f);
            float a = gns[tid]*rstd;
            kaf[0][tid] = a;
            kbf[tid] = gnb[tid] - mu*a;
        }
    }
    __syncthreads();                 // kaf/kbf ready

    // ==== phase 1: finish half-0 staging + halo zero ====
    stage_finish(0);
    if (tid < 384) {
        int c2 = tid & 31;
        int t3 = tid >> 5;           // 0..11
        int rr = t3 % 6;
        int e  = t3 / 6;             // 0..1
        int p  = rr*34 + e*33;
        int au = p*64 + swz8(c2 >> 2, p)*8 + (c2 & 3)*2;
        *(unsigned*)&lds_in[au] = 0u;
    }
    __syncthreads();                 // kc0 plane + halos ready

    // ==== phase 2: half-1 loads in flight under kc0 MFMA ====
    prim_load(1);
    mfma_kc(0);
    stage_finish(1);
    __syncthreads();                 // kc1 plane ready

    // ==== phase 3 ====
    mfma_kc(1);

    // ---- epilogue: write f16 out + per-block GN partials ----
    const int orow = rt*4 + r0;
#pragma unroll
    for (int mt = 0; mt < 2; ++mt) {
#pragma unroll
        for (int r = 0; r < 4; ++r) {
            int cout = mh*32 + mt*16 + quad*4 + r;
            float bs = bias[cout];
            const float* sp = smap + (size_t)cout*1024 + orow*32;
            u16* op = out + (((size_t)b*64 + cout)*32 + orow)*32;
            float v0 = acc[mt][0][r] + bs + tval*sp[n15];
            float v1 = acc[mt][1][r] + bs + tval*sp[16 + n15];
            op[n15]      = f2h(v0);
            op[16 + n15] = f2h(v1);
            float s = v0 + v1;
            float q = v0*v0 + v1*v1;
            s += __shfl_xor(s, 1); q += __shfl_xor(q, 1);
            s += __shfl_xor(s, 2); q += __shfl_xor(q, 2);
            s += __shfl_xor(s, 4); q += __shfl_xor(q, 4);
            s += __shfl_xor(s, 8); q += __shfl_xor(q, 8);
            if (n15 == 0) { ps[r0*64 + cout] = s; pss[r0*64 + cout] = q; }
        }
    }
    __syncthreads();
    if (tid < 64) {
        rg[tid]  = ps[tid]  + ps[64+tid]  + ps[128+tid]  + ps[192+tid];
        rgq[tid] = pss[tid] + pss[64+tid] + pss[128+tid] + pss[192+tid];
    }
    __syncthreads();
    if (tid < 32) {
        float S  = rg[2*tid]  + rg[2*tid+1];
        float SS = rgq[2*tid] + rgq[2*tid+1];
        float* pp = part + ((((size_t)slot_out*64 + b)*32 + tid)*NRT + rt)*2;
        pp[0] = S; pp[1] = SS;
    }
}

// ---------------------------------------------------------------------------
// Final combine (last step only): ydst = ysrc + sum_j (B_j*dt)*gn2affine(k_j).
// ---------------------------------------------------------------------------
__global__ __launch_bounds__(256) void final_combine_k(
    const float* __restrict__ ysrc, float* __restrict__ ydst,
    const u16* __restrict__ k0, const u16* __restrict__ k1,
    const u16* __restrict__ k2, const u16* __restrict__ k3,
    const u16* __restrict__ k4, const u16* __restrict__ k5,
    const float* __restrict__ part,
    const float* __restrict__ g2s, const float* __restrict__ g2b,
    float b0, float b1, float b2, float b3, float b4, float b5)
{
    const int bidx = blockIdx.x;
    const int b = bidx >> 6, ch = bidx & 63, g = ch >> 1;
    const int t = threadIdx.x;
    __shared__ float rs[6][2];
    if (t < 12) {
        int jj = t >> 1, st = t & 1;
        const float* pp = part + ((((size_t)(1+jj)*64 + b)*32 + g)*NRT)*2 + st;
        float v = 0.f;
#pragma unroll
        for (int q = 0; q < NRT; ++q) v += pp[2*q];
        rs[jj][st] = v;
    }
    __syncthreads();
    const float bb[6] = {b0, b1, b2, b3, b4, b5};
    float fa[6], fcs = 0.f;
#pragma unroll
    for (int jj = 0; jj < 6; ++jj) {
        float mu   = rs[jj][0] * (1.f/2048.f);
        float var  = rs[jj][1] * (1.f/2048.f) - mu*mu;
        float rstd = rsqrtf(var + 1e-5f);
        float a = g2s[ch]*rstd;
        float c = g2b[ch] - mu*a;
        fa[jj] = bb[jj]*a;
        fcs   += bb[jj]*c;
    }
    const size_t base = ((size_t)bidx*256 + t)*4;
    float4 r = *(const float4*)(ysrc + base);
    r.x += fcs; r.y += fcs; r.z += fcs; r.w += fcs;
    const u16* kp[6] = {k0, k1, k2, k3, k4, k5};
#pragma unroll
    for (int jj = 0; jj < 6; ++jj) {
        ushort4 kv = *(const ushort4*)(kp[jj] + base);
        r.x = fmaf(fa[jj], h2f(kv.x), r.x);
        r.y = fmaf(fa[jj], h2f(kv.y), r.y);
        r.z = fmaf(fa[jj], h2f(kv.z), r.z);
        r.w = fmaf(fa[jj], h2f(kv.w), r.w);
    }
    *(float4*)(ydst + base) = r;
}

// ---------------------------------------------------------------------------

static const double A_[5][5] = {
    {0.161, 0, 0, 0, 0},
    {-0.008480655492356989, 0.335480655492357, 0, 0, 0},
    {2.8971530571054935, -6.359448489975075, 4.3622954328695815, 0, 0},
    {5.325864828439257, -11.748883564062828, 7.4955393428898365, -0.09249506636175525, 0},
    {5.86145544294642, -12.92096931784711, 8.159367898576159, -0.071584973281401, -0.028269050394068383},
};
static const double B_[6] = {
    0.09646076681806523, 0.01, 0.4798896504144996,
    1.379008574103742, -3.290069515436081, 2.324710524099774,
};
static const double C_[5] = {0.161, 0.327, 0.9, 0.9800255409045097, 1.0};

extern "C" void kernel_launch(void* const* d_in, const int* in_sizes, int n_in,
                              void* d_out, int out_size, void* d_ws, size_t ws_size,
                              hipStream_t stream)
{
    const float* x   = (const float*)d_in[0];
    const float* c1w = (const float*)d_in[1];
    const float* c1b = (const float*)d_in[2];
    const float* g1s = (const float*)d_in[3];
    const float* g1b = (const float*)d_in[4];
    const float* c2w = (const float*)d_in[5];
    const float* c2b = (const float*)d_in[6];
    const float* g2s = (const float*)d_in[7];
    const float* g2b = (const float*)d_in[8];

    float* y  = (float*)d_out;
    u16*   wsb = (u16*)d_ws;
    u16*   h  = wsb;
    u16*   k[6];
    for (int i = 0; i < 6; ++i) k[i] = wsb + (size_t)(1 + i) * NELEM;
    u16*   wt1   = wsb + (size_t)7*NELEM;
    u16*   wt2   = wt1 + 73728;
    float* smap1 = (float*)(wt2 + 73728);
    float* smap2 = smap1 + 65536;
    float* part  = smap2 + 65536;    // 7*64*32*8*2 floats
    float* YA    = part + (size_t)7*64*32*8*2;
    float* YB    = YA + NELEM;
    float* yb[2] = {YA, YB};

    const double dt = 0.125;
    const float dtf = 0.125f;

    prep_w_k<<<18, 256, 0, stream>>>(c1w, wt1);
    prep_w_k<<<18, 256, 0, stream>>>(c2w, wt2);
    smap_k<<<256, 256, 0, stream>>>(c1w, smap1);
    smap_k<<<256, 256, 0, stream>>>(c2w, smap2);

    hipMemcpyAsync(YA, x, (size_t)NELEM * sizeof(float),
                   hipMemcpyDeviceToDevice, stream);

    const dim3 cgrid(NRT, BB);
    const float bw0 = (float)(B_[0]*dt), bw1 = (float)(B_[1]*dt),
                bw2 = (float)(B_[2]*dt), bw3 = (float)(B_[3]*dt),
                bw4 = (float)(B_[4]*dt), bw5 = (float)(B_[5]*dt);

    for (int s = 0; s < 8; ++s) {
        const float t0 = dtf * (float)s;
        const float* ys = yb[s & 1];

        // ---- stage 0 conv1 ----
        if (s == 0) {
            conv_mfma_k<0,0,false><<<cgrid, 512, 0, stream>>>(
                YA, nullptr, nullptr,nullptr,nullptr,nullptr,nullptr,nullptr,
                nullptr, part, g1s, g1b, g2s, g2b,
                wt1, smap1, c1b, h, t0, 0, 0,
                0.f,0.f,0.f,0.f,0.f,0.f);
        } else {
            // fused: y_s = y_{s-1} + sum_j (B_j*dt)*gn2(k_j^{s-1}); stage+write
            conv_mfma_k<1,6,true><<<cgrid, 512, 0, stream>>>(
                yb[(s-1)&1], nullptr, k[0],k[1],k[2],k[3],k[4],k[5],
                yb[s&1], part, g1s, g1b, g2s, g2b,
                wt1, smap1, c1b, h, t0, 0, 0,
                bw0, bw1, bw2, bw3, bw4, bw5);
        }
        conv_mfma_k<2,0,false><<<cgrid, 512, 0, stream>>>(
            nullptr, h, nullptr,nullptr,nullptr,nullptr,nullptr,nullptr,
            nullptr, part, g1s, g1b, g2s, g2b,
            wt2, smap2, c2b, k[0], t0, 0, 1,
            0.f,0.f,0.f,0.f,0.f,0.f);

        // ---- stages 1..5 ----
        for (int j = 1; j < 6; ++j) {
            const float tj = t0 + (float)C_[j-1] * dtf;
            float a[5] = {0,0,0,0,0};
            for (int i = 0; i < j; ++i) a[i] = (float)(A_[j-1][i] * dt);
            switch (j) {
            case 1:
                conv_mfma_k<1,1,false><<<cgrid, 512, 0, stream>>>(
                    ys, nullptr, k[0],k[1],k[2],k[3],k[4],k[5],
                    nullptr, part, g1s, g1b, g2s, g2b,
                    wt1, smap1, c1b, h, tj, 0, 0,
                    a[0],a[1],a[2],a[3],a[4],0.f); break;
            case 2:
                conv_mfma_k<1,2,false><<<cgrid, 512, 0, stream>>>(
                    ys, nullptr, k[0],k[1],k[2],k[3],k[4],k[5],
                    nullptr, part, g1s, g1b, g2s, g2b,
                    wt1, smap1, c1b, h, tj, 0, 0,
                    a[0],a[1],a[2],a[3],a[4],0.f); break;
            case 3:
                conv_mfma_k<1,3,false><<<cgrid, 512, 0, stream>>>(
                    ys, nullptr, k[0],k[1],k[2],k[3],k[4],k[5],
                    nullptr, part, g1s, g1b, g2s, g2b,
                    wt1, smap1, c1b, h, tj, 0, 0,
                    a[0],a[1],a[2],a[3],a[4],0.f); break;
            case 4:
                conv_mfma_k<1,4,false><<<cgrid, 512, 0, stream>>>(
                    ys, nullptr, k[0],k[1],k[2],k[3],k[4],k[5],
                    nullptr, part, g1s, g1b, g2s, g2b,
                    wt1, smap1, c1b, h, tj, 0, 0,
                    a[0],a[1],a[2],a[3],a[4],0.f); break;
            default:
                conv_mfma_k<1,5,false><<<cgrid, 512, 0, stream>>>(
                    ys, nullptr, k[0],k[1],k[2],k[3],k[4],k[5],
                    nullptr, part, g1s, g1b, g2s, g2b,
                    wt1, smap1, c1b, h, tj, 0, 0,
                    a[0],a[1],a[2],a[3],a[4],0.f); break;
            }
            conv_mfma_k<2,0,false><<<cgrid, 512, 0, stream>>>(
                nullptr, h, nullptr,nullptr,nullptr,nullptr,nullptr,nullptr,
                nullptr, part, g1s, g1b, g2s, g2b,
                wt2, smap2, c2b, k[j], tj, 0, 1 + j,
                0.f,0.f,0.f,0.f,0.f,0.f);
        }
    }
    // last step's combine -> d_out
    final_combine_k<<<4096, 256, 0, stream>>>(
        yb[7 & 1], y, k[0], k[1], k[2], k[3], k[4], k[5], part, g2s, g2b,
        bw0, bw1, bw2, bw3, bw4, bw5);
}